// Round 11
// baseline (340.374 us; speedup 1.0000x reference)
//
#include <hip/hip_runtime.h>
#include <stdint.h>

typedef unsigned int u32;
typedef _Float16 f16;
typedef __attribute__((ext_vector_type(16))) float    f32x16;
typedef __attribute__((ext_vector_type(4)))  float    f32x4;
typedef __attribute__((ext_vector_type(8)))  _Float16 f16x8;
typedef __attribute__((ext_vector_type(4)))  _Float16 f16x4;

#define DIM    1024
#define NROWS  8192
#define NLAYER 10

// ---------- weight packer: f32 W -> MFMA-fragment-ordered f16 chunks ----------
// Chunk (l, c32, kc): 1 KB. Lane holds A-operand frag of v_mfma_f32_32x32x16_f16:
//   W[c32*32 + (lane&31)][kc*16 + (lane>>5)*8 + j], j=0..7  (16 B per lane)
__global__ __launch_bounds__(256) void pack_weights(const float* __restrict__ W0,
                                                    const float* __restrict__ Wh,
                                                    f16* __restrict__ Wp) {
    int g    = blockIdx.x * 4 + (threadIdx.x >> 6);   // wave id = chunk id, 20480 total
    int lane = threadIdx.x & 63;
    int l    = g >> 11;
    int c32  = (g >> 6) & 31;
    int kc   = g & 63;
    int n  = c32 * 32 + (lane & 31);
    int k  = kc * 16 + (lane >> 5) * 8;
    const float* src = (l == 0 ? W0 : Wh + (size_t)(l - 1) * DIM * DIM) + (size_t)n * DIM + k;
    float4 w0 = *(const float4*)src;
    float4 w1 = *(const float4*)(src + 4);
    f16x8 o;
    o[0] = (f16)w0.x; o[1] = (f16)w0.y; o[2] = (f16)w0.z; o[3] = (f16)w0.w;
    o[4] = (f16)w1.x; o[5] = (f16)w1.y; o[6] = (f16)w1.z; o[7] = (f16)w1.w;
    *(f16x8*)((char*)Wp + (size_t)g * 1024 + lane * 16) = o;
}

// ---------- persistent row-local chain: 64 rows/block, in-place h ----------
// 128 blocks x 1024 threads (16 waves, 4/SIMD). h[64][1024] f16 in LDS,
// fragment-linear: frag(kc, rg) at ((kc*2+rg)*1024) + lane*16 (linear wave read).
// Wave w: cols [w*64,+64) (cg = 2w, 2w+1) x BOTH row-groups -> 4 MFMA/kc with
// 2x2 W/h reuse (halves per-row W traffic from L2 vs 32-row blocks).
// In-place h: barrier after k-loop (all reads done), epilogue overwrites, barrier.
__global__ __launch_bounds__(1024, 4) void mono_chain(
        const float* __restrict__ x,
        const f16* __restrict__ Wp,
        const float* __restrict__ b0g,
        const float* __restrict__ bh,
        const float* __restrict__ Wout,
        const float* __restrict__ bout,
        float* __restrict__ out) {
    __shared__ char lds[131072];   // h[64][1024] f16, fragment-linear

    const int tid  = threadIdx.x;
    const int lane = tid & 63;
    const int wid  = tid >> 6;        // 0..15
    const int r0   = blockIdx.x * 64;

    // ---- stage x rows -> h (f32 -> f16, fragment-linear) ----
    // row = lane: LDS writes are chunk-dense (2 lanes/bank = free)
    {
        const int rg = lane >> 5, rr = lane & 31;
        const float* src = x + (size_t)(r0 + lane) * DIM + wid * 64;
        #pragma unroll
        for (int i = 0; i < 16; ++i) {
            float4 v = *(const float4*)(src + i * 4);
            f16x4 o;
            o.x = (f16)v.x; o.y = (f16)v.y; o.z = (f16)v.z; o.w = (f16)v.w;
            int kc    = wid * 4 + (i >> 2);
            int khalf = (i >> 1) & 1;
            *(f16x4*)(lds + ((kc * 2 + rg) << 10) + (rr + (khalf << 5)) * 16 + (i & 1) * 8) = o;
        }
    }
    __syncthreads();

    const char* hL = lds + lane * 16;

    for (int l = 0; l < NLAYER; ++l) {
        const char* w0 = (const char*)Wp + (size_t)l * 2097152
                       + (size_t)wid * 131072 + lane * 16;
        const char* w1 = w0 + 65536;

        f32x16 acc00 = (f32x16)(0.f), acc01 = (f32x16)(0.f);
        f32x16 acc10 = (f32x16)(0.f), acc11 = (f32x16)(0.f);

        // depth-2 prefetch, named slots (rule #20)
        f16x8 wA0, wB0, wA1, wB1, hA0, hB0, hA1, hB1;
        wA0 = *(const f16x8*)(w0);
        wB0 = *(const f16x8*)(w1);
        hA0 = *(const f16x8*)(hL);
        hB0 = *(const f16x8*)(hL + 1024);
        wA1 = *(const f16x8*)(w0 + 1024);
        wB1 = *(const f16x8*)(w1 + 1024);
        hA1 = *(const f16x8*)(hL + 2048);
        hB1 = *(const f16x8*)(hL + 3072);

#define STEP(WA, WB, HA, HB, KN)                                                 \
        __builtin_amdgcn_s_setprio(1);                                           \
        acc00 = __builtin_amdgcn_mfma_f32_32x32x16_f16(WA, HA, acc00, 0, 0, 0);  \
        acc10 = __builtin_amdgcn_mfma_f32_32x32x16_f16(WB, HA, acc10, 0, 0, 0);  \
        acc01 = __builtin_amdgcn_mfma_f32_32x32x16_f16(WA, HB, acc01, 0, 0, 0);  \
        acc11 = __builtin_amdgcn_mfma_f32_32x32x16_f16(WB, HB, acc11, 0, 0, 0);  \
        __builtin_amdgcn_s_setprio(0);                                           \
        WA = *(const f16x8*)(w0 + (size_t)(KN) * 1024);                          \
        WB = *(const f16x8*)(w1 + (size_t)(KN) * 1024);                          \
        HA = *(const f16x8*)(hL + (size_t)(KN) * 2048);                          \
        HB = *(const f16x8*)(hL + (size_t)(KN) * 2048 + 1024);

        for (int t = 0; t < 31; ++t) {
            STEP(wA0, wB0, hA0, hB0, 2 * t + 2)
            STEP(wA1, wB1, hA1, hB1, 2 * t + 3)
        }
#undef STEP
        // tail: kc = 62 (slot0), kc = 63 (slot1)
        acc00 = __builtin_amdgcn_mfma_f32_32x32x16_f16(wA0, hA0, acc00, 0, 0, 0);
        acc10 = __builtin_amdgcn_mfma_f32_32x32x16_f16(wB0, hA0, acc10, 0, 0, 0);
        acc01 = __builtin_amdgcn_mfma_f32_32x32x16_f16(wA0, hB0, acc01, 0, 0, 0);
        acc11 = __builtin_amdgcn_mfma_f32_32x32x16_f16(wB0, hB0, acc11, 0, 0, 0);
        acc00 = __builtin_amdgcn_mfma_f32_32x32x16_f16(wA1, hA1, acc00, 0, 0, 0);
        acc10 = __builtin_amdgcn_mfma_f32_32x32x16_f16(wB1, hA1, acc10, 0, 0, 0);
        acc01 = __builtin_amdgcn_mfma_f32_32x32x16_f16(wA1, hB1, acc01, 0, 0, 0);
        acc11 = __builtin_amdgcn_mfma_f32_32x32x16_f16(wB1, hB1, acc11, 0, 0, 0);

        __syncthreads();   // ALL h reads done -> safe to overwrite in place

        // ---- epilogue: bias + sigmoid -> f16 back into the SAME buffer ----
        // D layout: row = (lane&31) + 32*rgp; col = (wid*2+cg)*32 + g2*8 + 4*(lane>>5) + j
        const float* bias = l ? (bh + (size_t)(l - 1) * DIM) : b0g;
        const int rD   = lane & 31;
        const int hsel = lane >> 5;
#define EPI(ACC, CG, RGP)                                                        \
        {                                                                        \
            _Pragma("unroll")                                                    \
            for (int g2 = 0; g2 < 4; ++g2) {                                     \
                int c = (wid * 2 + (CG)) * 32 + g2 * 8 + 4 * hsel;               \
                f32x4 bv = *(const f32x4*)(bias + c);                            \
                f16x4 o;                                                         \
                _Pragma("unroll")                                                \
                for (int j = 0; j < 4; ++j) {                                    \
                    float z = ACC[g2 * 4 + j] + bv[j];                           \
                    o[j] = (f16)(1.0f / (1.0f + __expf(-z)));                    \
                }                                                                \
                int kc2 = (wid * 2 + (CG)) * 2 + (g2 >> 1);                      \
                *(f16x4*)(lds + ((kc2 * 2 + (RGP)) << 10)                        \
                              + (rD + ((g2 & 1) << 5)) * 16 + hsel * 8) = o;     \
            }                                                                    \
        }
        EPI(acc00, 0, 0)
        EPI(acc01, 0, 1)
        EPI(acc10, 1, 0)
        EPI(acc11, 1, 1)
#undef EPI
        __syncthreads();   // h_next complete before next layer's reads
    }

    // ---- output gemv: h (in lds) -> out[r0..r0+63]; 16 threads per row ----
    {
        int row = tid >> 4;           // 0..63
        int seg = tid & 15;           // k in [seg*64, +64)
        int rg = row >> 5, rr = row & 31;
        float s = 0.f;
        #pragma unroll
        for (int i = 0; i < 8; ++i) {
            int k  = seg * 64 + i * 8;
            int kc = k >> 4;
            f16x8 h8 = *(const f16x8*)(lds + ((kc * 2 + rg) << 10)
                                           + (rr + ((i & 1) << 5)) * 16);
            const float* w = Wout + k;
            f32x4 w0 = *(const f32x4*)w;
            f32x4 w1 = *(const f32x4*)(w + 4);
            s += (float)h8[0] * w0[0] + (float)h8[1] * w0[1]
               + (float)h8[2] * w0[2] + (float)h8[3] * w0[3]
               + (float)h8[4] * w1[0] + (float)h8[5] * w1[1]
               + (float)h8[6] * w1[2] + (float)h8[7] * w1[3];
        }
        #pragma unroll
        for (int off = 8; off > 0; off >>= 1)
            s += __shfl_down(s, off, 16);
        if (seg == 0) out[r0 + row] = s + bout[0];
    }
}

// ---------- launcher ----------
extern "C" void kernel_launch(void* const* d_in, const int* in_sizes, int n_in,
                              void* d_out, int out_size, void* d_ws, size_t ws_size,
                              hipStream_t stream) {
    const float* x    = (const float*)d_in[0];
    const float* W0   = (const float*)d_in[1];
    const float* b0   = (const float*)d_in[2];
    const float* Wh   = (const float*)d_in[3];
    const float* bh   = (const float*)d_in[4];
    const float* Wout = (const float*)d_in[5];
    const float* bout = (const float*)d_in[6];
    float* out = (float*)d_out;

    f16* Wp = (f16*)d_ws;   // 20 MB packed weights

    pack_weights<<<NLAYER * 32 * 64 / 4, 256, 0, stream>>>(W0, Wh, Wp);
    mono_chain<<<NROWS / 64, 1024, 0, stream>>>(x, Wp, b0, bh, Wout, bout, out);
}